// Round 4
// baseline (57295.667 us; speedup 1.0000x reference)
//
#include <hip/hip_runtime.h>
#include <hip/hip_cooperative_groups.h>

namespace cg = cooperative_groups;

#define T_STEPS 512
#define HID 1024
#define SEQ_BSTRIDE (T_STEPS * HID)

// ===================== persistent cooperative kernel =====================
// LDS (dwords): wl [128 k][20] @0 (2560) ; zl [128 k][36] @2560 (4608)
// total 7168 dw = 28672 B  (<=32KB so 2 blocks/CU under 64KB accounting)
// epilogue reuse: partials [512 o][8 dw, swizzled] @0 (<=4120) ; gates [512] @4608
#define P_WSTR 20
#define P_ZL   2560
#define P_ZSTR 36
#define P_GLB  4608
#define P_LDS  7168

__launch_bounds__(256, 2)
__global__ void lstm_persist(const float* __restrict__ seq,
                             const float* __restrict__ Wh,
                             const float* __restrict__ Wx,
                             const float* __restrict__ Bias,
                             float* __restrict__ Ht,
                             float* __restrict__ dout)
{
    cg::grid_group grid = cg::this_grid();
    __shared__ float lds[P_LDS];

    const int tid   = threadIdx.x;
    const int blk   = blockIdx.x;
    const int layer = blk & 1;
    const int hblk  = blk >> 1;          // 0..255 -> h units hblk*4..+3

    // compute decomposition: tid = kg*8 + rowg*4 + bg
    const int kg   = tid >> 3;           // 0..31
    const int rowg = (tid >> 2) & 1;
    const int bg   = tid & 3;

    // staging ids
    const int srow = tid >> 4, skv = tid & 15;   // W: 16 rows x (16 k-octets)
    const int sdv  = tid >> 3, sb4 = tid & 7;    // z d-major
    const int sbb  = tid >> 3, sd8 = tid & 7;    // z b-major (seq)

    const float* whbase = Wh + (size_t)(((layer*4 + (srow>>2))<<10) + (hblk<<2) + (srow&3)) * 1024;
    const float* wxbase = Wx + (size_t)(((layer*4 + (srow>>2))<<10) + (hblk<<2) + (srow&3)) * 1024;

    // swizzled compute-side read bases (per-lane constant)
    const int swzW = ((kg>>3)&3) << 2;
    const int rA   = (rowg<<3) ^ swzW;
    const int wrb1 = kg*P_WSTR + rA;
    const int wrb2 = kg*P_WSTR + (rA^4);

    float c_reg = 0.f;
    const int act_hl = tid>>5, act_b = tid&31;
    float bf_=0.f, bw_=0.f, bi_=0.f, bo_=0.f;
    if (tid < 128) {
        const int h = (hblk<<2) + act_hl;
        bf_ = Bias[((layer*4+0)<<10) + h];
        bw_ = Bias[((layer*4+1)<<10) + h];
        bi_ = Bias[((layer*4+2)<<10) + h];
        bo_ = Bias[((layer*4+3)<<10) + h];
    }

    for (int p = 0; p <= T_STEPS; ++p) {
        const int t = layer ? (p-1) : p;
        if (t >= 0 && t < T_STEPS) {
            const int pIn = t & 1, pOut = pIn ^ 1;
            const float* zh   = Ht + ((pIn*2 + layer) << 15);
            const float* zx_d = Ht + ((pOut*2) << 15);
            const float* xseq = seq + (size_t)t * HID;
            float* hOut = Ht + ((pOut*2 + layer) << 15);

            float4 pfw0, pfw1, pfz[4];

            auto LOADC = [&](int c) {
                const float* wb = (c < 8) ? (whbase + (c<<7)) : (wxbase + ((c-8)<<7));
                pfw0 = *(const float4*)(wb + (skv<<3));
                pfw1 = *(const float4*)(wb + (skv<<3) + 4);
                if (c < 8 || layer == 1) {
                    const float* zsrc = (c < 8) ? (zh + (c<<12)) : (zx_d + ((c-8)<<12));
                    #pragma unroll
                    for (int j = 0; j < 4; ++j)
                        pfz[j] = *(const float4*)(zsrc + (((j<<5)+sdv)<<5) + (sb4<<2));
                } else {
                    const float* xs = xseq + (size_t)sbb * SEQ_BSTRIDE + ((c-8)<<7) + (sd8<<4);
                    #pragma unroll
                    for (int j = 0; j < 4; ++j)
                        pfz[j] = *(const float4*)(xs + (j<<2));
                }
            };

            auto WRITEC = [&](int c) {
                // W transpose, row-swizzled: swizzled_row = row ^ (((k>>3)&3)<<2)
                const int rs = srow ^ ((skv&3)<<2);
                const int kb = skv<<3;
                lds[(kb+0)*P_WSTR + rs] = pfw0.x;
                lds[(kb+1)*P_WSTR + rs] = pfw0.y;
                lds[(kb+2)*P_WSTR + rs] = pfw0.z;
                lds[(kb+3)*P_WSTR + rs] = pfw0.w;
                lds[(kb+4)*P_WSTR + rs] = pfw1.x;
                lds[(kb+5)*P_WSTR + rs] = pfw1.y;
                lds[(kb+6)*P_WSTR + rs] = pfw1.z;
                lds[(kb+7)*P_WSTR + rs] = pfw1.w;
                // z, b-swizzled: swizzled_b = b ^ (((d>>4)&7)<<2)
                if (c < 8 || layer == 1) {
                    #pragma unroll
                    for (int j = 0; j < 4; ++j) {
                        const int d   = (j<<5) + sdv;
                        const int swz = ((d>>4)&7) << 2;
                        *(float4*)&lds[P_ZL + d*P_ZSTR + ((sb4<<2) ^ swz)] = pfz[j];
                    }
                } else {
                    const int bcol = sbb ^ (sd8<<2);   // (d>>4)&7 == sd8 for all 16 d
                    #pragma unroll
                    for (int j = 0; j < 4; ++j) {
                        const int d0 = (sd8<<4) + (j<<2);
                        lds[P_ZL + (d0+0)*P_ZSTR + bcol] = pfz[j].x;
                        lds[P_ZL + (d0+1)*P_ZSTR + bcol] = pfz[j].y;
                        lds[P_ZL + (d0+2)*P_ZSTR + bcol] = pfz[j].z;
                        lds[P_ZL + (d0+3)*P_ZSTR + bcol] = pfz[j].w;
                    }
                }
            };

            float4 acc[8][2];
            #pragma unroll
            for (int r = 0; r < 8; ++r) {
                acc[r][0] = make_float4(0.f,0.f,0.f,0.f);
                acc[r][1] = make_float4(0.f,0.f,0.f,0.f);
            }

            LOADC(0);
            WRITEC(0);
            __syncthreads();

            for (int c = 0; c < 16; ++c) {
                if (c < 15) LOADC(c + 1);

                #pragma unroll
                for (int i = 0; i < 4; ++i) {
                    const int kk = i << 5;
                    const float4 wa  = *(const float4*)&lds[wrb1 + kk*P_WSTR];
                    const float4 wb2 = *(const float4*)&lds[wrb2 + kk*P_WSTR];
                    const int swzZ = (((kg>>4) + 2*i) & 7) << 2;
                    const int zb   = P_ZL + (kg + kk)*P_ZSTR;
                    const int boff = (bg<<3) ^ swzZ;
                    const float4 za = *(const float4*)&lds[zb + boff];
                    const float4 zc = *(const float4*)&lds[zb + (boff^4)];
                    const float wr[8] = {wa.x,wa.y,wa.z,wa.w, wb2.x,wb2.y,wb2.z,wb2.w};
                    #pragma unroll
                    for (int r = 0; r < 8; ++r) {
                        acc[r][0].x = fmaf(wr[r], za.x, acc[r][0].x);
                        acc[r][0].y = fmaf(wr[r], za.y, acc[r][0].y);
                        acc[r][0].z = fmaf(wr[r], za.z, acc[r][0].z);
                        acc[r][0].w = fmaf(wr[r], za.w, acc[r][0].w);
                        acc[r][1].x = fmaf(wr[r], zc.x, acc[r][1].x);
                        acc[r][1].y = fmaf(wr[r], zc.y, acc[r][1].y);
                        acc[r][1].z = fmaf(wr[r], zc.z, acc[r][1].z);
                        acc[r][1].w = fmaf(wr[r], zc.w, acc[r][1].w);
                    }
                }

                __syncthreads();
                if (c < 15) {
                    WRITEC(c + 1);
                    __syncthreads();
                }
            }

            // reduce over kg mod 8 within wave (lane bits 3..5)
            #pragma unroll
            for (int r = 0; r < 8; ++r) {
                #pragma unroll
                for (int q = 0; q < 2; ++q) {
                    float4 v = acc[r][q];
                    v.x += __shfl_xor(v.x, 8);  v.y += __shfl_xor(v.y, 8);
                    v.z += __shfl_xor(v.z, 8);  v.w += __shfl_xor(v.w, 8);
                    v.x += __shfl_xor(v.x, 16); v.y += __shfl_xor(v.y, 16);
                    v.z += __shfl_xor(v.z, 16); v.w += __shfl_xor(v.w, 16);
                    v.x += __shfl_xor(v.x, 32); v.y += __shfl_xor(v.y, 32);
                    v.z += __shfl_xor(v.z, 32); v.w += __shfl_xor(v.w, 32);
                    acc[r][q] = v;
                }
            }

            // cross-wave partials (swizzled) in lds[0..4119]
            const int wv = tid >> 6;
            if ((tid & 56) == 0) {
                #pragma unroll
                for (int r = 0; r < 8; ++r) {
                    const float vals[8] = {acc[r][0].x, acc[r][0].y, acc[r][0].z, acc[r][0].w,
                                           acc[r][1].x, acc[r][1].y, acc[r][1].z, acc[r][1].w};
                    #pragma unroll
                    for (int b2 = 0; b2 < 8; ++b2) {
                        const int o  = ((rowg * 8 + r) << 5) + bg * 8 + b2;
                        const int sw = ((o >> 3) & 3) * 4 + ((o >> 8) & 1) * 16;
                        lds[o * 8 + sw + wv] = vals[b2];
                    }
                }
            }
            __syncthreads();

            // sum the 4 wave-partials
            #pragma unroll
            for (int ii = 0; ii < 2; ++ii) {
                const int o  = tid + (ii << 8);
                const int sw = ((o >> 3) & 3) * 4 + ((o >> 8) & 1) * 16;
                const float4 pq = *(const float4*)&lds[o * 8 + sw];
                lds[P_GLB + o] = pq.x + pq.y + pq.z + pq.w;
            }
            __syncthreads();

            // activations + state update (c persistent in registers)
            if (tid < 128) {
                const float gf = lds[P_GLB + (0*4 + act_hl)*32 + act_b] + bf_;
                const float gw = lds[P_GLB + (1*4 + act_hl)*32 + act_b] + bw_;
                const float gi = lds[P_GLB + (2*4 + act_hl)*32 + act_b] + bi_;
                const float go = lds[P_GLB + (3*4 + act_hl)*32 + act_b] + bo_;
                const int h    = (hblk<<2) + act_hl;
                const int sidx = (h<<5) + act_b;
                const float sf  = 1.f / (1.f + __expf(-gf));
                const float sw2 = 1.f / (1.f + __expf(-gw));
                const float ti  = tanhf(gi);
                const float so  = 1.f / (1.f + __expf(-go));
                const float c_new = c_reg * sf + sw2 * ti;
                const float h_new = tanhf(c_new) * so;
                c_reg = c_new;
                hOut[sidx] = h_new;
                if (layer == 1 && t == T_STEPS - 1)
                    dout[act_b * HID + h] = h_new;
            }
            __syncthreads();
        }

        __threadfence();
        grid.sync();
    }
}

// ===================== fallback: round-2 per-step kernel (proven) =====================
#define F_WSTR 20
#define F_ZL 5120
#define F_ZSTR 36
#define F_GLB 4608
#define F_LDS 14336

__launch_bounds__(256, 1)
__global__ void lstm_step_fb(const float* __restrict__ seq,
                             const float* __restrict__ Wh,
                             const float* __restrict__ Wx,
                             const float* __restrict__ Bias,
                             float* __restrict__ Ht,
                             float* __restrict__ C,
                             float* __restrict__ dout,
                             int t, int l, int write_out)
{
    __shared__ float lds[F_LDS];
    const int tid = threadIdx.x;
    const int bid = blockIdx.x;

    const int kg   = tid >> 3;
    const int rowg = (tid >> 2) & 1;
    const int bg   = tid & 3;

    const int pIn = t & 1, pOut = pIn ^ 1;
    const float* zh   = Ht + ((pIn * 2 + l) << 15);
    const float* zx_d = Ht + ((pOut * 2) << 15);
    float* hOut = Ht + ((pOut * 2 + l) << 15);
    float* cPtr = C + (l << 15);

    const int srow = tid >> 4;
    const int skv  = tid & 15;
    const int sdv  = tid >> 3;
    const int sb4  = tid & 7;
    const int sb   = tid >> 3;
    const int sd8  = tid & 7;

    const float* whbase = Wh + ((size_t)(((l * 4 + (srow >> 2)) << 10) + (bid << 2) + (srow & 3))) * 1024;
    const float* wxbase = Wx + ((size_t)(((l * 4 + (srow >> 2)) << 10) + (bid << 2) + (srow & 3))) * 1024;

    float4 pfw[4];
    float4 pfz[8];

    auto LOADC = [&](int c) {
        const float* wb = (c < 4) ? (whbase + c * 256) : (wxbase + (c - 4) * 256);
        #pragma unroll
        for (int j = 0; j < 4; ++j)
            pfw[j] = *(const float4*)(wb + j * 64 + skv * 4);
        if (c < 4) {
            const float* zsrc = zh + (c << 8) * 32;
            #pragma unroll
            for (int j = 0; j < 8; ++j)
                pfz[j] = *(const float4*)(zsrc + (j * 32 + sdv) * 32 + sb4 * 4);
        } else if (l == 1) {
            const float* zsrc = zx_d + ((c - 4) << 8) * 32;
            #pragma unroll
            for (int j = 0; j < 8; ++j)
                pfz[j] = *(const float4*)(zsrc + (j * 32 + sdv) * 32 + sb4 * 4);
        } else {
            const float* xs = seq + (size_t)sb * SEQ_BSTRIDE + t * HID + (c - 4) * 256;
            #pragma unroll
            for (int j = 0; j < 8; ++j)
                pfz[j] = *(const float4*)(xs + j * 32 + sd8 * 4);
        }
    };

    auto WRITEC = [&](int c) {
        #pragma unroll
        for (int j = 0; j < 4; ++j) {
            const int kk = j * 64 + skv * 4;
            lds[(kk + 0) * F_WSTR + srow] = pfw[j].x;
            lds[(kk + 1) * F_WSTR + srow] = pfw[j].y;
            lds[(kk + 2) * F_WSTR + srow] = pfw[j].z;
            lds[(kk + 3) * F_WSTR + srow] = pfw[j].w;
        }
        if (c < 4 || l == 1) {
            #pragma unroll
            for (int j = 0; j < 8; ++j)
                *(float4*)&lds[F_ZL + (j * 32 + sdv) * F_ZSTR + sb4 * 4] = pfz[j];
        } else {
            #pragma unroll
            for (int j = 0; j < 8; ++j) {
                const int dd = j * 32 + sd8 * 4;
                lds[F_ZL + (dd + 0) * F_ZSTR + sb] = pfz[j].x;
                lds[F_ZL + (dd + 1) * F_ZSTR + sb] = pfz[j].y;
                lds[F_ZL + (dd + 2) * F_ZSTR + sb] = pfz[j].z;
                lds[F_ZL + (dd + 3) * F_ZSTR + sb] = pfz[j].w;
            }
        }
    };

    float4 acc[8][2];
    #pragma unroll
    for (int r = 0; r < 8; ++r) {
        acc[r][0] = make_float4(0.f, 0.f, 0.f, 0.f);
        acc[r][1] = make_float4(0.f, 0.f, 0.f, 0.f);
    }

    LOADC(0);
    WRITEC(0);
    __syncthreads();

    const int wbase = kg * F_WSTR + rowg * 8;
    const int zbase = F_ZL + kg * F_ZSTR + bg * 8;

    for (int c = 0; c < 8; ++c) {
        if (c < 7) LOADC(c + 1);

        #pragma unroll
        for (int i = 0; i < 8; ++i) {
            const float* wp = &lds[wbase + i * (32 * F_WSTR)];
            const float* zp = &lds[zbase + i * (32 * F_ZSTR)];
            const float4 wa  = *(const float4*)(wp);
            const float4 wb2 = *(const float4*)(wp + 4);
            const float4 za  = *(const float4*)(zp);
            const float4 zb2 = *(const float4*)(zp + 4);
            const float wr[8] = {wa.x, wa.y, wa.z, wa.w, wb2.x, wb2.y, wb2.z, wb2.w};
            #pragma unroll
            for (int r = 0; r < 8; ++r) {
                acc[r][0].x = fmaf(wr[r], za.x,  acc[r][0].x);
                acc[r][0].y = fmaf(wr[r], za.y,  acc[r][0].y);
                acc[r][0].z = fmaf(wr[r], za.z,  acc[r][0].z);
                acc[r][0].w = fmaf(wr[r], za.w,  acc[r][0].w);
                acc[r][1].x = fmaf(wr[r], zb2.x, acc[r][1].x);
                acc[r][1].y = fmaf(wr[r], zb2.y, acc[r][1].y);
                acc[r][1].z = fmaf(wr[r], zb2.z, acc[r][1].z);
                acc[r][1].w = fmaf(wr[r], zb2.w, acc[r][1].w);
            }
        }

        __syncthreads();
        if (c < 7) {
            WRITEC(c + 1);
            __syncthreads();
        }
    }

    #pragma unroll
    for (int r = 0; r < 8; ++r) {
        #pragma unroll
        for (int q = 0; q < 2; ++q) {
            float4 v = acc[r][q];
            v.x += __shfl_xor(v.x, 8);  v.y += __shfl_xor(v.y, 8);
            v.z += __shfl_xor(v.z, 8);  v.w += __shfl_xor(v.w, 8);
            v.x += __shfl_xor(v.x, 16); v.y += __shfl_xor(v.y, 16);
            v.z += __shfl_xor(v.z, 16); v.w += __shfl_xor(v.w, 16);
            v.x += __shfl_xor(v.x, 32); v.y += __shfl_xor(v.y, 32);
            v.z += __shfl_xor(v.z, 32); v.w += __shfl_xor(v.w, 32);
            acc[r][q] = v;
        }
    }

    const int wv = tid >> 6;
    if ((tid & 56) == 0) {
        #pragma unroll
        for (int r = 0; r < 8; ++r) {
            const float vals[8] = {acc[r][0].x, acc[r][0].y, acc[r][0].z, acc[r][0].w,
                                   acc[r][1].x, acc[r][1].y, acc[r][1].z, acc[r][1].w};
            #pragma unroll
            for (int b2 = 0; b2 < 8; ++b2) {
                const int o  = ((rowg * 8 + r) << 5) + bg * 8 + b2;
                const int sw = ((o >> 3) & 3) * 4 + ((o >> 8) & 1) * 16;
                lds[o * 8 + sw + wv] = vals[b2];
            }
        }
    }
    __syncthreads();

    #pragma unroll
    for (int ii = 0; ii < 2; ++ii) {
        const int o  = tid + ii * 256;
        const int sw = ((o >> 3) & 3) * 4 + ((o >> 8) & 1) * 16;
        const float4 pq = *(const float4*)&lds[o * 8 + sw];
        float s = pq.x + pq.y + pq.z + pq.w;
        const int row = o >> 5;
        const int g = row >> 2, hl = row & 3;
        s += Bias[((l * 4 + g) << 10) + (bid << 2) + hl];
        lds[F_GLB + o] = s;
    }
    __syncthreads();

    if (tid < 128) {
        const int hl = tid >> 5, b = tid & 31;
        const float gf = lds[F_GLB + (0 * 4 + hl) * 32 + b];
        const float gw = lds[F_GLB + (1 * 4 + hl) * 32 + b];
        const float gi = lds[F_GLB + (2 * 4 + hl) * 32 + b];
        const float go = lds[F_GLB + (3 * 4 + hl) * 32 + b];
        const int h = (bid << 2) + hl;
        const int sidx = (h << 5) + b;
        const float c_old = cPtr[sidx];
        const float sf = 1.f / (1.f + __expf(-gf));
        const float sw2 = 1.f / (1.f + __expf(-gw));
        const float ti = tanhf(gi);
        const float so = 1.f / (1.f + __expf(-go));
        const float c_new = c_old * sf + sw2 * ti;
        const float h_new = tanhf(c_new) * so;
        cPtr[sidx] = c_new;
        hOut[sidx] = h_new;
        if (write_out) dout[b * HID + h] = h_new;
    }
}

extern "C" void kernel_launch(void* const* d_in, const int* in_sizes, int n_in,
                              void* d_out, int out_size, void* d_ws, size_t ws_size,
                              hipStream_t stream) {
    const float* seq  = (const float*)d_in[0];
    const float* Wh   = (const float*)d_in[1];
    const float* Wx   = (const float*)d_in[2];
    const float* Bias = (const float*)d_in[3];
    float* Ht   = (float*)d_ws;                  // [2 parity][2 layer][1024][32]
    float* C    = Ht + 131072;                   // fallback cell state
    float* dout = (float*)d_out;

    hipMemsetAsync(d_ws, 0, (size_t)(131072 + 65536) * sizeof(float), stream);

    void* args[] = {(void*)&seq, (void*)&Wh, (void*)&Wx, (void*)&Bias,
                    (void*)&Ht, (void*)&dout};
    hipError_t err = hipLaunchCooperativeKernel((const void*)lstm_persist,
                                                dim3(512), dim3(256), args, 0, stream);
    if (err != hipSuccess) {
        // fallback: proven per-step kernel (round-2), ~29 ms
        for (int t = 0; t < T_STEPS; ++t) {
            for (int l = 0; l < 2; ++l) {
                const int wo = (t == T_STEPS - 1 && l == 1) ? 1 : 0;
                lstm_step_fb<<<dim3(256), dim3(256), 0, stream>>>(
                    seq, Wh, Wx, Bias, Ht, C, dout, t, l, wo);
            }
        }
    }
}